// Round 2
// baseline (104.639 us; speedup 1.0000x reference)
//
#include <hip/hip_runtime.h>
#include <hip/hip_cooperative_groups.h>

namespace cg = cooperative_groups;

#define NTOT 768
#define NHALF 384
#define DDIM 64
#define NPER 200
#define PPAD 256
#define NKER 4
#define NMB 12       // m-blocks of 64 rows (gemm)
#define NKH 2        // split-K halves (gemm)
#define NB_GEMM 384  // 12 mb * 4 nc * 4 k * 2 kh
#define NPART (NMB * NKH)
#define NTILE 12     // 768/64 K-build tiles per dim
#define LDSROW 68    // float stride per staged row: 16B-aligned, 2-way-max banks
#define NBLK_FUSED 388  // max(phase1 344, phase2 388, phase3 200)

typedef __attribute__((ext_vector_type(8))) short short8;    // 8 bf16 (4 VGPR)
typedef __attribute__((ext_vector_type(4))) float floatx4;   // MFMA acc

constexpr int K0SZ  = NTOT * NTOT;
constexpr int OF_KH = 0;                                  // bf16 K [4][768][768] (ushort) - gemm A
constexpr int KH_FLOATS = NKER * K0SZ / 2;
constexpr int OF_P   = OF_KH + KH_FLOATS;                 // fp32 row-sum partials [4][12][768]
constexpr int OF_C   = OF_P + NKER * NTILE * NTOT;        // fp32 packed [384][4k]
constexpr int OF_ROWM = OF_C + NKER * NHALF;              // fp32 packed [768][4k]
constexpr int OF_COLM = OF_ROWM + NKER * NTOT;            // fp32 packed [768][4k]
constexpr int OF_SCAL = OF_COLM + NKER * NTOT;
constexpr int OF_STT  = OF_SCAL + 16;                     // bf16 S^T [PPAD][NTOT]
constexpr int STT_FLOATS = PPAD * NTOT / 2;
constexpr int OF_Q0P  = OF_STT + STT_FLOATS;              // fp32 [4][NPART][PPAD]
constexpr int OF_KH2  = OF_Q0P + NKER * NPART * PPAD;     // bf16 packed [768][768][4k] - gather plane

__device__ __forceinline__ unsigned short f2bf(float f) {  // RTN
    unsigned int u = __float_as_uint(f);
    return (unsigned short)((u + 0x7FFFu + ((u >> 16) & 1u)) >> 16);
}
__device__ __forceinline__ float bf2f(unsigned short h) {
    return __uint_as_float(((unsigned int)h) << 16);
}

// ============ phase 1: scatter STT (bid<200) or 64x64 K tile build (bid-200) ============
__device__ __forceinline__ void phase1_body(int bid, int tid, float* smem,
                                            const float* __restrict__ X,
                                            const float* __restrict__ Y,
                                            const float* __restrict__ bw,
                                            const int* __restrict__ perms,
                                            float* __restrict__ ws) {
    float* zb  = smem;
    float* nrm = smem + 128 * LDSROW;
    unsigned short* STT = (unsigned short*)(ws + OF_STT);
    unsigned short* KH  = (unsigned short*)(ws + OF_KH);
    unsigned short* KH2 = (unsigned short*)(ws + OF_KH2);

    if (bid < NPER) {
        if (tid < 192) {
            ((uint2*)(STT + bid * NTOT))[tid] = make_uint2(0u, 0u);
            if (bid < PPAD - NPER)
                ((uint2*)(STT + (NPER + bid) * NTOT))[tid] = make_uint2(0u, 0u);
        }
        __syncthreads();
        int v = perms[bid * NTOT + tid];
        STT[bid * NTOT + v] = 0x3F80;  // bf16 1.0
        if (tid < NHALF - 256) {
            int v2 = perms[bid * NTOT + 256 + tid];
            STT[bid * NTOT + v2] = 0x3F80;
        }
        return;  // fused caller: safe, no further block-level sync inside this body
    }

    int t  = bid - NPER;           // 0..143
    int at = t / NTILE, bt = t % NTILE;
    int a0 = at * 64, b0 = bt * 64;
    int ta = tid >> 4, tb = tid & 15;

    float ib2[NKER], ib1[NKER];
#pragma unroll
    for (int k = 0; k < NKER; ++k) { float b = bw[k]; ib2[k] = 1.f / (b * b); ib1[k] = 1.f / b; }

#pragma unroll
    for (int it = 0; it < 8; ++it) {
        int idx = it * 256 + tid;
        int j = idx >> 4, qf = idx & 15;
        int g = (j < 64) ? a0 + j : b0 + (j - 64);
        const float* zr = (g < NHALF) ? X + g * DDIM : Y + (g - NHALF) * DDIM;
        *(float4*)(zb + j * LDSROW + qf * 4) = *(const float4*)(zr + qf * 4);
    }
    __syncthreads();
    if (tid < 128) {
        float s = 0.f;
        const float* zr = zb + tid * LDSROW;
#pragma unroll
        for (int d = 0; d < DDIM; d += 4) {
            float4 zv = *(const float4*)(zr + d);
            s += zv.x * zv.x + zv.y * zv.y + zv.z * zv.z + zv.w * zv.w;
        }
        nrm[tid] = s;
    }
    __syncthreads();

    float acc[4][4];
#pragma unroll
    for (int r = 0; r < 4; ++r)
#pragma unroll
        for (int c = 0; c < 4; ++c) acc[r][c] = 0.f;
#pragma unroll
    for (int s = 0; s < 16; ++s) {
        float4 av[4], bv[4];
#pragma unroll
        for (int r = 0; r < 4; ++r) av[r] = *(const float4*)(zb + (ta * 4 + r) * LDSROW + s * 4);
#pragma unroll
        for (int c = 0; c < 4; ++c) bv[c] = *(const float4*)(zb + (64 + tb * 4 + c) * LDSROW + s * 4);
#pragma unroll
        for (int r = 0; r < 4; ++r)
#pragma unroll
            for (int c = 0; c < 4; ++c) {
                acc[r][c] = fmaf(av[r].x, bv[c].x, acc[r][c]);
                acc[r][c] = fmaf(av[r].y, bv[c].y, acc[r][c]);
                acc[r][c] = fmaf(av[r].z, bv[c].z, acc[r][c]);
                acc[r][c] = fmaf(av[r].w, bv[c].w, acc[r][c]);
            }
    }

    float rs[4][NKER];
#pragma unroll
    for (int r = 0; r < 4; ++r)
#pragma unroll
        for (int k = 0; k < NKER; ++k) rs[r][k] = 0.f;

#pragma unroll
    for (int r = 0; r < 4; ++r) {
        int a = a0 + ta * 4 + r;
        unsigned short h[4][4];   // [c][k], fully unrolled -> registers
#pragma unroll
        for (int c = 0; c < 4; ++c) {
            int b = b0 + tb * 4 + c;
            float d2 = (nrm[ta * 4 + r] + nrm[64 + tb * 4 + c]) - 2.f * acc[r][c];
            if (b == a) d2 = 0.f;
            d2 = fmaxf(d2, 0.f);
            float d2e = d2 + 1e-12f;
            float dist = sqrtf(d2e);
#pragma unroll
            for (int k = 0; k < NKER; ++k) {
                float val = ((k & 1) == 0) ? __expf(-d2e * ib2[k]) : __expf(-dist * ib1[k]);
                rs[r][k] += val;
                h[c][k] = f2bf(val);
                if (bt == at + 6 && tb == ta && c == r)   // b == a+384, a<384
                    ws[OF_C + a * 4 + k] = val;           // packed [a][4k]
            }
        }
        // gemm layout: [k][a][b], ushort4 along b
#pragma unroll
        for (int k = 0; k < NKER; ++k) {
            ushort4 us;
            us.x = h[0][k]; us.y = h[1][k]; us.z = h[2][k]; us.w = h[3][k];
            *(ushort4*)(KH + k * K0SZ + a * NTOT + b0 + tb * 4) = us;
        }
        // gather layout: [a][b][4k], two 16B stores (c0,c1 | c2,c3)
        {
            unsigned short* p2 = KH2 + (a * NTOT + b0 + tb * 4) * 4;
            short8 lo, hi;
#pragma unroll
            for (int k = 0; k < NKER; ++k) {
                lo[k]     = (short)h[0][k];
                lo[4 + k] = (short)h[1][k];
                hi[k]     = (short)h[2][k];
                hi[4 + k] = (short)h[3][k];
            }
            *(short8*)(p2)     = lo;
            *(short8*)(p2 + 8) = hi;
        }
    }

#pragma unroll
    for (int off = 8; off > 0; off >>= 1)
#pragma unroll
        for (int r = 0; r < 4; ++r)
#pragma unroll
            for (int k = 0; k < NKER; ++k) rs[r][k] += __shfl_down(rs[r][k], off, 64);
    if (tb == 0) {
#pragma unroll
        for (int k = 0; k < NKER; ++k) {
            float4 pv = make_float4(rs[0][k], rs[1][k], rs[2][k], rs[3][k]);
            *(float4*)(ws + OF_P + (k * NTILE + bt) * NTOT + a0 + ta * 4) = pv;
        }
    }
}

// ============ phase 2: split-K gemm (bid<384) or final (k=bid-384) ============
__device__ __forceinline__ void phase2_body(int bid, int tid, float* smem,
                                            const float* __restrict__ bw,
                                            float* __restrict__ ws,
                                            float* __restrict__ out) {
    int wave = tid >> 6, lane = tid & 63;

    if (bid < NB_GEMM) {
        int mb = bid % NMB;
        int t  = bid / NMB;
        int nc = t & 3;
        int t2 = t >> 2;
        int k  = t2 & 3;
        int kh = t2 >> 2;
        int m0 = mb * 64 + wave * 16;
        int n0 = nc * 64;
        int row = lane & 15, quad = lane >> 4;
        const unsigned short* KH  = (const unsigned short*)(ws + OF_KH);
        const unsigned short* STT = (const unsigned short*)(ws + OF_STT);
        const unsigned short* aptr = KH + k * K0SZ + (m0 + row) * NTOT + quad * 8;
        floatx4 acc[4][2];
#pragma unroll
        for (int j = 0; j < 4; ++j)
#pragma unroll
            for (int h = 0; h < 2; ++h) acc[j][h] = (floatx4){0.f, 0.f, 0.f, 0.f};
        int kk0 = kh * (NTOT / 2);
        for (int kk = kk0; kk < kk0 + NTOT / 2; kk += 64) {
            short8 a0 = *(const short8*)(aptr + kk);
            short8 a1 = *(const short8*)(aptr + kk + 32);
#pragma unroll
            for (int j = 0; j < 4; ++j) {
                const unsigned short* bp = STT + (n0 + j * 16 + row) * NTOT + quad * 8 + kk;
                short8 b0 = *(const short8*)(bp);
                short8 b1 = *(const short8*)(bp + 32);
                acc[j][0] = __builtin_amdgcn_mfma_f32_16x16x32_bf16(a0, b0, acc[j][0], 0, 0, 0);
                acc[j][1] = __builtin_amdgcn_mfma_f32_16x16x32_bf16(a1, b1, acc[j][1], 0, 0, 0);
            }
        }
        __syncthreads();
#pragma unroll
        for (int j = 0; j < 4; ++j) {
            const unsigned short* sp = STT + (n0 + j * 16 + row) * NTOT + m0 + quad * 4;
            float p = 0.f;
#pragma unroll
            for (int r = 0; r < 4; ++r) p += (acc[j][0][r] + acc[j][1][r]) * bf2f(sp[r]);
            p += __shfl_down(p, 32, 64);
            p += __shfl_down(p, 16, 64);
            if (lane < 16) smem[wave * 64 + j * 16 + lane] = p;
        }
        __syncthreads();
        if (tid < 64) {
            float s = smem[tid] + smem[64 + tid] + smem[128 + tid] + smem[192 + tid];
            ws[OF_Q0P + (k * NPART + kh * NMB + mb) * PPAD + n0 + tid] = s;
        }
        return;
    }

    int k = bid - NB_GEMM;
    const float* Pk = ws + OF_P + k * (NTILE * NTOT);
    float v[5] = {0.f, 0.f, 0.f, 0.f, 0.f};
    for (int a = tid; a < NTOT; a += 256) {
        float rsx = 0.f, rsy = 0.f;
#pragma unroll
        for (int j = 0; j < 6; ++j)  rsx += Pk[j * NTOT + a];
#pragma unroll
        for (int j = 6; j < 12; ++j) rsy += Pk[j * NTOT + a];
        float rs0 = rsx + rsy;
        float cx = (a < NHALF)  ? ws[OF_C + a * 4 + k] : 0.f;
        float cy = (a >= NHALF) ? ws[OF_C + (a - NHALF) * 4 + k] : 0.f;
        ws[OF_ROWM + a * 4 + k] = rs0 - cx;   // packed [a][4k]
        ws[OF_COLM + a * 4 + k] = rs0 - cy;   // packed [a][4k]
        v[0] += rs0;
        if (a < NHALF) { v[1] += cx; v[2] += rsx; v[4] += rsy; }
        else           { v[3] += rsy; }
    }
#pragma unroll
    for (int off = 32; off > 0; off >>= 1)
#pragma unroll
        for (int j = 0; j < 5; ++j) v[j] += __shfl_down(v[j], off, 64);
    __syncthreads();
    if (lane == 0)
#pragma unroll
        for (int j = 0; j < 5; ++j) smem[wave * 8 + j] = v[j];
    __syncthreads();
    if (tid == 0) {
        float tot0 = smem[0] + smem[8] + smem[16] + smem[24];
        float csum = smem[1] + smem[9] + smem[17] + smem[25];
        float sxx  = smem[2] + smem[10] + smem[18] + smem[26];
        float syy  = smem[3] + smem[11] + smem[19] + smem[27];
        float sxy  = smem[4] + smem[12] + smem[20] + smem[28];
        float b = bw[k];
        float dist0 = sqrtf(1e-12f);
        float dk = ((k & 1) == 0) ? expf(-(dist0 * dist0) / (b * b)) : expf(-dist0 / b);
        ws[OF_SCAL + k * 4 + 0] = tot0 - csum;
        ws[OF_SCAL + k * 4 + 1] = dk;
        double U = ((double)sxx - 384.0 * (double)dk) * (1.0 / 147072.0)
                 + ((double)syy - 384.0 * (double)dk) * (1.0 / 147072.0)
                 - 2.0 * ((double)sxy - (double)csum) * (1.0 / 147456.0);
        out[k * 201] = (float)U;
    }
}

// ============ phase 3: per-perm gathered sums, QUAD-k per block ============
// 200 blocks; every gather (KH2/ROWM/COLM/C) serves all 4 kernels in one load.
__device__ __forceinline__ void phase3_body(int bid, int tid, float* smem,
                                            const int* __restrict__ perms,
                                            const float* __restrict__ ws,
                                            float* __restrict__ out) {
    if (bid >= NPER) return;
    int wave = tid >> 6, lane = tid & 63;
    int p = bid;
    const unsigned short* STT = (const unsigned short*)(ws + OF_STT);
    const unsigned short* KH2 = (const unsigned short*)(ws + OF_KH2);
    float v[NKER][4];   // per kernel: rs, cs, pair, qc
#pragma unroll
    for (int k = 0; k < NKER; ++k)
#pragma unroll
        for (int j = 0; j < 4; ++j) v[k][j] = 0.f;

    for (int i = tid; i < NHALF; i += 256) {
        int a  = perms[p * NTOT + i];
        int bY = perms[p * NTOT + NHALF + i];
        float ss = bf2f(STT[p * NTOT + i]) * bf2f(STT[p * NTOT + NHALF + i]);
        bool diag = (a < NHALF) && (bY == a + NHALF);
        float4 rw = *(const float4*)(ws + OF_ROWM + a * 4);
        float4 cl = *(const float4*)(ws + OF_COLM + a * 4);
        float4 cc = *(const float4*)(ws + OF_C + i * 4);
        ushort4 kv = *(const ushort4*)(KH2 + (a * NTOT + bY) * 4);
        float rwk[4] = {rw.x, rw.y, rw.z, rw.w};
        float clk[4] = {cl.x, cl.y, cl.z, cl.w};
        float cck[4] = {cc.x, cc.y, cc.z, cc.w};
        float kvk[4] = {bf2f(kv.x), bf2f(kv.y), bf2f(kv.z), bf2f(kv.w)};
#pragma unroll
        for (int k = 0; k < NKER; ++k) {
            v[k][0] += rwk[k];
            v[k][1] += clk[k];
            v[k][2] += diag ? 0.f : kvk[k];
            v[k][3] += cck[k] * ss;
        }
    }
#pragma unroll
    for (int off = 32; off > 0; off >>= 1)
#pragma unroll
        for (int k = 0; k < NKER; ++k)
#pragma unroll
            for (int j = 0; j < 4; ++j) v[k][j] += __shfl_down(v[k][j], off, 64);
    if (lane == 0)
#pragma unroll
        for (int k = 0; k < NKER; ++k)
#pragma unroll
            for (int j = 0; j < 4; ++j) smem[wave * 16 + k * 4 + j] = v[k][j];

    // Q0P partial sums: wave w handles kernel k=w, lanes 0..23 load, 32-lane reduce
    float q = 0.f;
    if (lane < NPART) q = ws[OF_Q0P + (wave * NPART + lane) * PPAD + p];
#pragma unroll
    for (int off = 16; off > 0; off >>= 1) q += __shfl_down(q, off, 32);
    if (lane == 0) smem[64 + wave] = q;
    __syncthreads();

    if (tid < NKER) {
        int k = tid;
        float rsf = 0.f, csf = 0.f, pairf = 0.f, qcf = 0.f;
#pragma unroll
        for (int w = 0; w < 4; ++w) {
            rsf   += smem[w * 16 + k * 4 + 0];
            csf   += smem[w * 16 + k * 4 + 1];
            pairf += smem[w * 16 + k * 4 + 2];
            qcf   += smem[w * 16 + k * 4 + 3];
        }
        double rs = (double)rsf, cs = (double)csf, pair = (double)pairf, qc = (double)qcf;
        double total_mod = (double)ws[OF_SCAL + k * 4 + 0];
        double dk        = (double)ws[OF_SCAL + k * 4 + 1];
        double qd = (double)smem[64 + k] - qc;
        double sXX = qd - 384.0 * dk;
        double sYY = total_mod - rs - cs + qd - 384.0 * dk;
        double sXY = rs - qd - pair;
        out[k * 201 + 1 + p] =
            (float)(sXX * (1.0 / 147072.0) + sYY * (1.0 / 147072.0) - 2.0 * sXY * (1.0 / 147456.0));
    }
}

// ============ fused cooperative kernel: 3 launches -> 1 launch + 2 grid syncs ============
// 388 blocks x 256 thr; co-residency needs 2 blocks/CU: LDS 35KB -> 4/CU,
// launch_bounds(256,2) caps VGPR at 256 -> >=2/CU. Checked host-side before coop launch.
__global__ __launch_bounds__(256, 2) void k_fused(const float* __restrict__ X,
                                                  const float* __restrict__ Y,
                                                  const float* __restrict__ bw,
                                                  const int* __restrict__ perms,
                                                  float* __restrict__ ws,
                                                  float* __restrict__ out) {
    __shared__ float smem[128 * LDSROW + 128];   // 35 KB; phases 2/3 reuse the prefix
    cg::grid_group grid = cg::this_grid();
    int bid = blockIdx.x, tid = threadIdx.x;

    if (bid < NPER + NTILE * NTILE) phase1_body(bid, tid, smem, X, Y, bw, perms, ws);
    __threadfence();   // device-scope: make KH/KH2/STT/P/C visible across XCD L2s
    grid.sync();

    if (bid < NB_GEMM + NKER) phase2_body(bid, tid, smem, bw, ws, out);
    __threadfence();
    grid.sync();

    phase3_body(bid, tid, smem, perms, ws, out);
}

// ============ fallback standalone kernels (same bodies, 3 launches) ============
__global__ __launch_bounds__(256) void k_s1(const float* __restrict__ X,
                                            const float* __restrict__ Y,
                                            const float* __restrict__ bw,
                                            const int* __restrict__ perms,
                                            float* __restrict__ ws) {
    __shared__ float smem[128 * LDSROW + 128];
    phase1_body(blockIdx.x, threadIdx.x, smem, X, Y, bw, perms, ws);
}

__global__ __launch_bounds__(256) void k_s2(const float* __restrict__ bw,
                                            float* __restrict__ ws, float* __restrict__ out) {
    __shared__ float smem[256];
    phase2_body(blockIdx.x, threadIdx.x, smem, bw, ws, out);
}

__global__ __launch_bounds__(256) void k_s3(const int* __restrict__ perms,
                                            const float* __restrict__ ws,
                                            float* __restrict__ out) {
    __shared__ float smem[128];
    phase3_body(blockIdx.x, threadIdx.x, smem, perms, ws, out);
}

extern "C" void kernel_launch(void* const* d_in, const int* in_sizes, int n_in,
                              void* d_out, int out_size, void* d_ws, size_t ws_size,
                              hipStream_t stream) {
    const float* X     = (const float*)d_in[0];
    const float* Y     = (const float*)d_in[1];
    const float* bw    = (const float*)d_in[2];
    const int*   perms = (const int*)d_in[3];
    float* ws  = (float*)d_ws;
    float* out = (float*)d_out;

    // Decide coop viability once (pure occupancy query: capture-safe, no stream ops).
    static int coop_ok = -1;
    if (coop_ok < 0) {
        int nb = 0;
        hipError_t e = hipOccupancyMaxActiveBlocksPerMultiprocessor(&nb, k_fused, 256, 0);
        coop_ok = (e == hipSuccess && nb >= 2) ? 1 : 0;   // 2 blocks/CU x 256 CU = 512 >= 388
    }
    if (coop_ok == 1) {
        void* args[6] = {(void*)&X, (void*)&Y, (void*)&bw, (void*)&perms, (void*)&ws, (void*)&out};
        if (hipLaunchCooperativeKernel(k_fused, dim3(NBLK_FUSED), dim3(256), args, 0u, stream)
            == hipSuccess)
            return;
        coop_ok = 0;   // fall through to 3-launch path permanently
    }
    k_s1<<<NPER + NTILE * NTILE, 256, 0, stream>>>(X, Y, bw, perms, ws);
    k_s2<<<NB_GEMM + NKER, 256, 0, stream>>>(bw, ws, out);
    k_s3<<<NPER, 256, 0, stream>>>(perms, ws, out);
}

// Round 3
// 98.510 us; speedup vs baseline: 1.0622x; 1.0622x over previous
//
#include <hip/hip_runtime.h>
#include <hip/hip_cooperative_groups.h>

namespace cg = cooperative_groups;

#define NTOT 768
#define NHALF 384
#define DDIM 64
#define NPER 200
#define PPAD 256
#define NKER 4
#define NMB 12       // m-blocks of 64 rows (gemm)
#define NKH 2        // split-K halves (gemm)
#define NB_GEMM 384  // 12 mb * 4 nc * 4 k * 2 kh
#define NPART (NMB * NKH)
#define NTILE 12     // 768/64 b-tiles (K-build cols)
#define NRT 24       // 768/32 row-tiles (K-build rows) -- 288 heavy blocks, ~1.1/CU
#define LDSROW 68    // float stride per staged row: 16B-aligned, 2-way-max banks
#define NBLK_FUSED 488  // max(phase1 488, phase2 388, phase3 400); <=512 co-resident @2/CU

typedef __attribute__((ext_vector_type(8))) short short8;    // 8 bf16 (4 VGPR)
typedef __attribute__((ext_vector_type(4))) float floatx4;   // MFMA acc

constexpr int K0SZ  = NTOT * NTOT;
constexpr int OF_KH = 0;                                  // bf16 K [4][768][768] (ushort)
constexpr int KH_FLOATS = NKER * K0SZ / 2;
constexpr int OF_P   = OF_KH + KH_FLOATS;                 // fp32 row-sum partials [4][12][768]
constexpr int OF_C   = OF_P + NKER * NTILE * NTOT;        // fp32 [4][384]
constexpr int OF_ROWM = OF_C + NKER * NHALF;              // fp32 [4][768]
constexpr int OF_COLM = OF_ROWM + NKER * NTOT;            // fp32 [4][768]
constexpr int OF_SCAL = OF_COLM + NKER * NTOT;
constexpr int OF_STT  = OF_SCAL + 16;                     // bf16 S^T [PPAD][NTOT]
constexpr int STT_FLOATS = PPAD * NTOT / 2;
constexpr int OF_Q0P  = OF_STT + STT_FLOATS;              // fp32 [4][NPART][PPAD]

__device__ __forceinline__ unsigned short f2bf(float f) {  // RTN
    unsigned int u = __float_as_uint(f);
    return (unsigned short)((u + 0x7FFFu + ((u >> 16) & 1u)) >> 16);
}
__device__ __forceinline__ float bf2f(unsigned short h) {
    return __uint_as_float(((unsigned int)h) << 16);
}

// ============ phase 1: scatter STT (bid<200) or 32x64 K tile build (bid-200) ============
// Row-split tiles (32 rows x 64 cols): 288 heavy blocks instead of 144 -> full CU
// coverage during the longest phase. Per-row compute order identical to the 64x64
// version, so outputs are bit-identical.
__device__ __forceinline__ void phase1_body(int bid, int tid, float* smem,
                                            const float* __restrict__ X,
                                            const float* __restrict__ Y,
                                            const float* __restrict__ bw,
                                            const int* __restrict__ perms,
                                            float* __restrict__ ws) {
    float* zb  = smem;
    float* nrm = smem + 96 * LDSROW;
    unsigned short* STT = (unsigned short*)(ws + OF_STT);
    unsigned short* KH  = (unsigned short*)(ws + OF_KH);

    if (bid < NPER) {
        if (tid < 192) {
            ((uint2*)(STT + bid * NTOT))[tid] = make_uint2(0u, 0u);
            if (bid < PPAD - NPER)
                ((uint2*)(STT + (NPER + bid) * NTOT))[tid] = make_uint2(0u, 0u);
        }
        __syncthreads();
        int v = perms[bid * NTOT + tid];
        STT[bid * NTOT + v] = 0x3F80;  // bf16 1.0
        if (tid < NHALF - 256) {
            int v2 = perms[bid * NTOT + 256 + tid];
            STT[bid * NTOT + v2] = 0x3F80;
        }
        return;  // fused caller: safe, no further block-level sync inside this body
    }

    int t  = bid - NPER;           // 0..287
    int rt = t / NTILE, bt = t % NTILE;
    int r0 = rt * 32, b0 = bt * 64;
    int ta = tid >> 4, tb = tid & 15;

    float ib2[NKER], ib1[NKER];
#pragma unroll
    for (int k = 0; k < NKER; ++k) { float b = bw[k]; ib2[k] = 1.f / (b * b); ib1[k] = 1.f / b; }

    // stage 32 a-rows + 64 b-rows of Z (96 rows x 64 f32)
#pragma unroll
    for (int it = 0; it < 6; ++it) {
        int idx = it * 256 + tid;       // 0..1535
        int j = idx >> 4, qf = idx & 15;
        int g = (j < 32) ? r0 + j : b0 + (j - 32);
        const float* zr = (g < NHALF) ? X + g * DDIM : Y + (g - NHALF) * DDIM;
        *(float4*)(zb + j * LDSROW + qf * 4) = *(const float4*)(zr + qf * 4);
    }
    __syncthreads();
    if (tid < 96) {
        float s = 0.f;
        const float* zr = zb + tid * LDSROW;
#pragma unroll
        for (int d = 0; d < DDIM; d += 4) {
            float4 zv = *(const float4*)(zr + d);
            s += zv.x * zv.x + zv.y * zv.y + zv.z * zv.z + zv.w * zv.w;
        }
        nrm[tid] = s;
    }
    __syncthreads();

    // 2x4 register micro-tile per thread (rows ta*2+r, cols tb*4+c)
    float acc[2][4];
#pragma unroll
    for (int r = 0; r < 2; ++r)
#pragma unroll
        for (int c = 0; c < 4; ++c) acc[r][c] = 0.f;
#pragma unroll
    for (int s = 0; s < 16; ++s) {
        float4 av[2], bv[4];
#pragma unroll
        for (int r = 0; r < 2; ++r) av[r] = *(const float4*)(zb + (ta * 2 + r) * LDSROW + s * 4);
#pragma unroll
        for (int c = 0; c < 4; ++c) bv[c] = *(const float4*)(zb + (32 + tb * 4 + c) * LDSROW + s * 4);
#pragma unroll
        for (int r = 0; r < 2; ++r)
#pragma unroll
            for (int c = 0; c < 4; ++c) {
                acc[r][c] = fmaf(av[r].x, bv[c].x, acc[r][c]);
                acc[r][c] = fmaf(av[r].y, bv[c].y, acc[r][c]);
                acc[r][c] = fmaf(av[r].z, bv[c].z, acc[r][c]);
                acc[r][c] = fmaf(av[r].w, bv[c].w, acc[r][c]);
            }
    }

    float rs[2][NKER];
#pragma unroll
    for (int r = 0; r < 2; ++r)
#pragma unroll
        for (int k = 0; k < NKER; ++k) rs[r][k] = 0.f;

#pragma unroll
    for (int r = 0; r < 2; ++r) {
        int a = r0 + ta * 2 + r;
        unsigned short h[4][4];   // [c][k], fully unrolled -> registers
#pragma unroll
        for (int c = 0; c < 4; ++c) {
            int b = b0 + tb * 4 + c;
            float d2 = (nrm[ta * 2 + r] + nrm[32 + tb * 4 + c]) - 2.f * acc[r][c];
            if (b == a) d2 = 0.f;
            d2 = fmaxf(d2, 0.f);
            float d2e = d2 + 1e-12f;
            float dist = sqrtf(d2e);
#pragma unroll
            for (int k = 0; k < NKER; ++k) {
                float val = ((k & 1) == 0) ? __expf(-d2e * ib2[k]) : __expf(-dist * ib1[k]);
                rs[r][k] += val;
                h[c][k] = f2bf(val);
                if (a < NHALF && b == a + NHALF)          // diagonal partner K(a, a+384)
                    ws[OF_C + k * NHALF + a] = val;
            }
        }
#pragma unroll
        for (int k = 0; k < NKER; ++k) {
            ushort4 us;
            us.x = h[0][k]; us.y = h[1][k]; us.z = h[2][k]; us.w = h[3][k];
            *(ushort4*)(KH + k * K0SZ + a * NTOT + b0 + tb * 4) = us;
        }
    }

#pragma unroll
    for (int off = 8; off > 0; off >>= 1)
#pragma unroll
        for (int r = 0; r < 2; ++r)
#pragma unroll
            for (int k = 0; k < NKER; ++k) rs[r][k] += __shfl_down(rs[r][k], off, 64);
    if (tb == 0) {
#pragma unroll
        for (int k = 0; k < NKER; ++k) {
            float2 pv = make_float2(rs[0][k], rs[1][k]);
            *(float2*)(ws + OF_P + (k * NTILE + bt) * NTOT + r0 + ta * 2) = pv;
        }
    }
}

// ============ phase 2: split-K gemm (bid<384) or final (k=bid-384) ============
__device__ __forceinline__ void phase2_body(int bid, int tid, float* smem,
                                            const float* __restrict__ bw,
                                            float* __restrict__ ws,
                                            float* __restrict__ out) {
    int wave = tid >> 6, lane = tid & 63;

    if (bid < NB_GEMM) {
        int mb = bid % NMB;
        int t  = bid / NMB;
        int nc = t & 3;
        int t2 = t >> 2;
        int k  = t2 & 3;
        int kh = t2 >> 2;
        int m0 = mb * 64 + wave * 16;
        int n0 = nc * 64;
        int row = lane & 15, quad = lane >> 4;
        const unsigned short* KH  = (const unsigned short*)(ws + OF_KH);
        const unsigned short* STT = (const unsigned short*)(ws + OF_STT);
        const unsigned short* aptr = KH + k * K0SZ + (m0 + row) * NTOT + quad * 8;
        floatx4 acc[4][2];
#pragma unroll
        for (int j = 0; j < 4; ++j)
#pragma unroll
            for (int h = 0; h < 2; ++h) acc[j][h] = (floatx4){0.f, 0.f, 0.f, 0.f};
        int kk0 = kh * (NTOT / 2);
        for (int kk = kk0; kk < kk0 + NTOT / 2; kk += 64) {
            short8 a0 = *(const short8*)(aptr + kk);
            short8 a1 = *(const short8*)(aptr + kk + 32);
#pragma unroll
            for (int j = 0; j < 4; ++j) {
                const unsigned short* bp = STT + (n0 + j * 16 + row) * NTOT + quad * 8 + kk;
                short8 b0 = *(const short8*)(bp);
                short8 b1 = *(const short8*)(bp + 32);
                acc[j][0] = __builtin_amdgcn_mfma_f32_16x16x32_bf16(a0, b0, acc[j][0], 0, 0, 0);
                acc[j][1] = __builtin_amdgcn_mfma_f32_16x16x32_bf16(a1, b1, acc[j][1], 0, 0, 0);
            }
        }
        __syncthreads();
#pragma unroll
        for (int j = 0; j < 4; ++j) {
            const unsigned short* sp = STT + (n0 + j * 16 + row) * NTOT + m0 + quad * 4;
            float p = 0.f;
#pragma unroll
            for (int r = 0; r < 4; ++r) p += (acc[j][0][r] + acc[j][1][r]) * bf2f(sp[r]);
            p += __shfl_down(p, 32, 64);
            p += __shfl_down(p, 16, 64);
            if (lane < 16) smem[wave * 64 + j * 16 + lane] = p;
        }
        __syncthreads();
        if (tid < 64) {
            float s = smem[tid] + smem[64 + tid] + smem[128 + tid] + smem[192 + tid];
            ws[OF_Q0P + (k * NPART + kh * NMB + mb) * PPAD + n0 + tid] = s;
        }
        return;
    }

    int k = bid - NB_GEMM;
    const float* Pk = ws + OF_P + k * (NTILE * NTOT);
    float v[5] = {0.f, 0.f, 0.f, 0.f, 0.f};
    for (int a = tid; a < NTOT; a += 256) {
        float rsx = 0.f, rsy = 0.f;
#pragma unroll
        for (int j = 0; j < 6; ++j)  rsx += Pk[j * NTOT + a];
#pragma unroll
        for (int j = 6; j < 12; ++j) rsy += Pk[j * NTOT + a];
        float rs0 = rsx + rsy;
        float cx = (a < NHALF)  ? ws[OF_C + k * NHALF + a] : 0.f;
        float cy = (a >= NHALF) ? ws[OF_C + k * NHALF + a - NHALF] : 0.f;
        ws[OF_ROWM + k * NTOT + a] = rs0 - cx;
        ws[OF_COLM + k * NTOT + a] = rs0 - cy;
        v[0] += rs0;
        if (a < NHALF) { v[1] += cx; v[2] += rsx; v[4] += rsy; }
        else           { v[3] += rsy; }
    }
#pragma unroll
    for (int off = 32; off > 0; off >>= 1)
#pragma unroll
        for (int j = 0; j < 5; ++j) v[j] += __shfl_down(v[j], off, 64);
    __syncthreads();
    if (lane == 0)
#pragma unroll
        for (int j = 0; j < 5; ++j) smem[wave * 8 + j] = v[j];
    __syncthreads();
    if (tid == 0) {
        float tot0 = smem[0] + smem[8] + smem[16] + smem[24];
        float csum = smem[1] + smem[9] + smem[17] + smem[25];
        float sxx  = smem[2] + smem[10] + smem[18] + smem[26];
        float syy  = smem[3] + smem[11] + smem[19] + smem[27];
        float sxy  = smem[4] + smem[12] + smem[20] + smem[28];
        float b = bw[k];
        float dist0 = sqrtf(1e-12f);
        float dk = ((k & 1) == 0) ? expf(-(dist0 * dist0) / (b * b)) : expf(-dist0 / b);
        ws[OF_SCAL + k * 4 + 0] = tot0 - csum;
        ws[OF_SCAL + k * 4 + 1] = dk;
        double U = ((double)sxx - 384.0 * (double)dk) * (1.0 / 147072.0)
                 + ((double)syy - 384.0 * (double)dk) * (1.0 / 147072.0)
                 - 2.0 * ((double)sxy - (double)csum) * (1.0 / 147456.0);
        out[k * 201] = (float)U;
    }
}

// ============ phase 3: per-perm gathered sums, dual-k per block ============
// 400 blocks: p = bid%200, handles k = bid/200 and k+2 (shares perm/STT loads).
__device__ __forceinline__ void phase3_body(int bid, int tid, float* smem,
                                            const int* __restrict__ perms,
                                            const float* __restrict__ ws,
                                            float* __restrict__ out) {
    if (bid >= 2 * NPER) return;
    int wave = tid >> 6, lane = tid & 63;
    int p  = bid % NPER;
    int kb = bid / NPER;          // 0 or 1
    int k0 = kb, k1 = kb + 2;
    const unsigned short* STT = (const unsigned short*)(ws + OF_STT);
    const unsigned short* KH  = (const unsigned short*)(ws + OF_KH);
    float v0[4] = {0.f, 0.f, 0.f, 0.f};   // rs, cs, pair, qc for k0
    float v1[4] = {0.f, 0.f, 0.f, 0.f};   // same for k1
    for (int i = tid; i < NHALF; i += 256) {
        int a  = perms[p * NTOT + i];
        int bY = perms[p * NTOT + NHALF + i];
        float ss = bf2f(STT[p * NTOT + i]) * bf2f(STT[p * NTOT + NHALF + i]);
        bool diag = (a < NHALF) && (bY == a + NHALF);
        v0[0] += ws[OF_ROWM + k0 * NTOT + a];
        v0[1] += ws[OF_COLM + k0 * NTOT + a];
        float kv0 = bf2f(KH[k0 * K0SZ + a * NTOT + bY]);
        v0[2] += diag ? 0.f : kv0;
        v0[3] += ws[OF_C + k0 * NHALF + i] * ss;
        v1[0] += ws[OF_ROWM + k1 * NTOT + a];
        v1[1] += ws[OF_COLM + k1 * NTOT + a];
        float kv1 = bf2f(KH[k1 * K0SZ + a * NTOT + bY]);
        v1[2] += diag ? 0.f : kv1;
        v1[3] += ws[OF_C + k1 * NHALF + i] * ss;
    }
#pragma unroll
    for (int off = 32; off > 0; off >>= 1)
#pragma unroll
        for (int j = 0; j < 4; ++j) {
            v0[j] += __shfl_down(v0[j], off, 64);
            v1[j] += __shfl_down(v1[j], off, 64);
        }
    if (lane == 0)
#pragma unroll
        for (int j = 0; j < 4; ++j) {
            smem[wave * 8 + j]     = v0[j];
            smem[wave * 8 + 4 + j] = v1[j];
        }
    // lane-parallel Q0P partial sums (24 partials each), wave 0 lanes 0..23
    float q0 = 0.f, q1 = 0.f;
    if (tid < NPART) {
        q0 = ws[OF_Q0P + (k0 * NPART + tid) * PPAD + p];
        q1 = ws[OF_Q0P + (k1 * NPART + tid) * PPAD + p];
    }
#pragma unroll
    for (int off = 16; off > 0; off >>= 1) {
        q0 += __shfl_down(q0, off, 32);
        q1 += __shfl_down(q1, off, 32);
    }
    __syncthreads();
    if (tid == 0) {
#pragma unroll
        for (int kk = 0; kk < 2; ++kk) {
            int k = (kk == 0) ? k0 : k1;
            int o = (kk == 0) ? 0 : 4;
            float qsumf = (kk == 0) ? q0 : q1;
            double rs   = (double)(smem[o + 0] + smem[o + 8] + smem[o + 16] + smem[o + 24]);
            double cs   = (double)(smem[o + 1] + smem[o + 9] + smem[o + 17] + smem[o + 25]);
            double pair = (double)(smem[o + 2] + smem[o + 10] + smem[o + 18] + smem[o + 26]);
            double qc   = (double)(smem[o + 3] + smem[o + 11] + smem[o + 19] + smem[o + 27]);
            double total_mod = (double)ws[OF_SCAL + k * 4 + 0];
            double dk        = (double)ws[OF_SCAL + k * 4 + 1];
            double q = (double)qsumf - qc;
            double sXX = q - 384.0 * dk;
            double sYY = total_mod - rs - cs + q - 384.0 * dk;
            double sXY = rs - q - pair;
            out[k * 201 + 1 + p] =
                (float)(sXX * (1.0 / 147072.0) + sYY * (1.0 / 147072.0) - 2.0 * sXY * (1.0 / 147456.0));
        }
    }
}

// ============ fused cooperative kernel: 3 launches -> 1 launch + 2 grid syncs ============
// 488 blocks x 256 thr; co-residency needs 2 blocks/CU: LDS 35KB -> 4/CU,
// launch_bounds(256,2) caps VGPR at 256 -> >=2/CU. Checked host-side before coop launch.
__global__ __launch_bounds__(256, 2) void k_fused(const float* __restrict__ X,
                                                  const float* __restrict__ Y,
                                                  const float* __restrict__ bw,
                                                  const int* __restrict__ perms,
                                                  float* __restrict__ ws,
                                                  float* __restrict__ out) {
    __shared__ float smem[128 * LDSROW + 128];   // 35 KB; phases 2/3 reuse the prefix
    cg::grid_group grid = cg::this_grid();
    int bid = blockIdx.x, tid = threadIdx.x;

    phase1_body(bid, tid, smem, X, Y, bw, perms, ws);
    __threadfence();   // device-scope: make KH/STT/P/C visible across XCD L2s
    grid.sync();

    if (bid < NB_GEMM + NKER) phase2_body(bid, tid, smem, bw, ws, out);
    __threadfence();
    grid.sync();

    phase3_body(bid, tid, smem, perms, ws, out);
}

// ============ fallback standalone kernels (same bodies, 3 launches) ============
__global__ __launch_bounds__(256) void k_s1(const float* __restrict__ X,
                                            const float* __restrict__ Y,
                                            const float* __restrict__ bw,
                                            const int* __restrict__ perms,
                                            float* __restrict__ ws) {
    __shared__ float smem[128 * LDSROW + 128];
    phase1_body(blockIdx.x, threadIdx.x, smem, X, Y, bw, perms, ws);
}

__global__ __launch_bounds__(256) void k_s2(const float* __restrict__ bw,
                                            float* __restrict__ ws, float* __restrict__ out) {
    __shared__ float smem[256];
    phase2_body(blockIdx.x, threadIdx.x, smem, bw, ws, out);
}

__global__ __launch_bounds__(256) void k_s3(const int* __restrict__ perms,
                                            const float* __restrict__ ws,
                                            float* __restrict__ out) {
    __shared__ float smem[64];
    phase3_body(blockIdx.x, threadIdx.x, smem, perms, ws, out);
}

extern "C" void kernel_launch(void* const* d_in, const int* in_sizes, int n_in,
                              void* d_out, int out_size, void* d_ws, size_t ws_size,
                              hipStream_t stream) {
    const float* X     = (const float*)d_in[0];
    const float* Y     = (const float*)d_in[1];
    const float* bw    = (const float*)d_in[2];
    const int*   perms = (const int*)d_in[3];
    float* ws  = (float*)d_ws;
    float* out = (float*)d_out;

    // Decide coop viability once (pure occupancy query: capture-safe, no stream ops).
    static int coop_ok = -1;
    if (coop_ok < 0) {
        int nb = 0;
        hipError_t e = hipOccupancyMaxActiveBlocksPerMultiprocessor(&nb, k_fused, 256, 0);
        coop_ok = (e == hipSuccess && nb >= 2) ? 1 : 0;   // 2 blocks/CU x 256 CU = 512 >= 488
    }
    if (coop_ok == 1) {
        void* args[6] = {(void*)&X, (void*)&Y, (void*)&bw, (void*)&perms, (void*)&ws, (void*)&out};
        if (hipLaunchCooperativeKernel(k_fused, dim3(NBLK_FUSED), dim3(256), args, 0u, stream)
            == hipSuccess)
            return;
        coop_ok = 0;   // fall through to 3-launch path permanently
    }
    k_s1<<<NPER + NRT * NTILE, 256, 0, stream>>>(X, Y, bw, perms, ws);
    k_s2<<<NB_GEMM + NKER, 256, 0, stream>>>(bw, ws, out);
    k_s3<<<2 * NPER, 256, 0, stream>>>(perms, ws, out);
}

// Round 4
// 93.466 us; speedup vs baseline: 1.1195x; 1.0540x over previous
//
#include <hip/hip_runtime.h>
#include <hip/hip_cooperative_groups.h>

namespace cg = cooperative_groups;

#define NTOT 768
#define NHALF 384
#define DDIM 64
#define NPER 200
#define PPAD 256
#define NKER 4
#define NMB 12       // m-blocks of 64 rows (gemm)
#define NKH 2        // split-K halves (gemm)
#define NB_GEMM 384  // 12 mb * 4 nc * 4 k * 2 kh
#define NPART (NMB * NKH)
#define NTILE 12     // 768/64 b-tiles (K-build cols)
#define NRT 16       // 768/48 row-tiles (K-build rows)
#define NHB (NRT * NTILE)   // 192 heavy blocks <= 256 CUs -> <=1 heavy/CU
#define TROWS 48
#define LDSROW 68    // float stride per staged row: 16B-aligned
#define NBLK_FUSED 400  // max(phase1 392, phase2 388, phase3 400); <=512 co-resident @2/CU

typedef __attribute__((ext_vector_type(8))) short short8;    // 8 bf16 (4 VGPR)
typedef __attribute__((ext_vector_type(4))) float floatx4;   // MFMA acc

constexpr int K0SZ  = NTOT * NTOT;
constexpr int OF_KH = 0;                                  // bf16 K [4][768][768] (ushort)
constexpr int KH_FLOATS = NKER * K0SZ / 2;
constexpr int OF_P   = OF_KH + KH_FLOATS;                 // fp32 row-sum partials [4][12][768]
constexpr int OF_C   = OF_P + NKER * NTILE * NTOT;        // fp32 [4][384]
constexpr int OF_ROWM = OF_C + NKER * NHALF;              // fp32 [4][768]
constexpr int OF_COLM = OF_ROWM + NKER * NTOT;            // fp32 [4][768]
constexpr int OF_SCAL = OF_COLM + NKER * NTOT;
constexpr int OF_STT  = OF_SCAL + 16;                     // bf16 S^T [PPAD][NTOT]
constexpr int STT_FLOATS = PPAD * NTOT / 2;
constexpr int OF_Q0P  = OF_STT + STT_FLOATS;              // fp32 [4][NPART][PPAD]

__device__ __forceinline__ unsigned short f2bf(float f) {  // RTN
    unsigned int u = __float_as_uint(f);
    return (unsigned short)((u + 0x7FFFu + ((u >> 16) & 1u)) >> 16);
}
__device__ __forceinline__ float bf2f(unsigned short h) {
    return __uint_as_float(((unsigned int)h) << 16);
}
// XOR bank swizzle: spreads stride-4-row column reads across 8 bank groups.
// posf is the float offset within a row (multiple of 4 -> 16B alignment kept).
__device__ __forceinline__ int swz(int row, int posf) {
    return posf ^ (((row >> 2) & 7) << 2);
}

// ============ phase 1: 48x64 K tile build (bid<192) or scatter STT (bid-192) ============
// Heavy tiles FIRST in the grid so the breadth-first dispatcher lands <=1 heavy/CU.
// Per-row summation tree identical to previous versions -> bit-identical outputs.
__device__ __forceinline__ void phase1_body(int bid, int tid, float* smem,
                                            const float* __restrict__ X,
                                            const float* __restrict__ Y,
                                            const float* __restrict__ bw,
                                            const int* __restrict__ perms,
                                            float* __restrict__ ws) {
    float* zb  = smem;
    float* nrm = smem + 112 * LDSROW;
    unsigned short* STT = (unsigned short*)(ws + OF_STT);
    unsigned short* KH  = (unsigned short*)(ws + OF_KH);

    if (bid >= NHB) {
        int sb = bid - NHB;
        if (sb >= NPER) return;
        if (tid < 192) {
            ((uint2*)(STT + sb * NTOT))[tid] = make_uint2(0u, 0u);
            if (sb < PPAD - NPER)
                ((uint2*)(STT + (NPER + sb) * NTOT))[tid] = make_uint2(0u, 0u);
        }
        __syncthreads();
        int v = perms[sb * NTOT + tid];
        STT[sb * NTOT + v] = 0x3F80;  // bf16 1.0
        if (tid < NHALF - 256) {
            int v2 = perms[sb * NTOT + 256 + tid];
            STT[sb * NTOT + v2] = 0x3F80;
        }
        return;  // fused caller: safe, no further block-level sync inside this body
    }

    int rt = bid / NTILE, bt = bid % NTILE;
    int r0 = rt * TROWS, b0 = bt * 64;
    int ta = tid >> 4, tb = tid & 15;

    float ib2[NKER], ib1[NKER];
#pragma unroll
    for (int k = 0; k < NKER; ++k) { float b = bw[k]; ib2[k] = 1.f / (b * b); ib1[k] = 1.f / b; }

    // stage 48 a-rows + 64 b-rows of Z (112 rows x 64 f32), bank-swizzled
#pragma unroll
    for (int it = 0; it < 7; ++it) {
        int idx = it * 256 + tid;       // 0..1791 = 112 rows x 16 float4
        int j = idx >> 4, qf = idx & 15;
        int g = (j < TROWS) ? r0 + j : b0 + (j - TROWS);
        const float* zr = (g < NHALF) ? X + g * DDIM : Y + (g - NHALF) * DDIM;
        *(float4*)(zb + j * LDSROW + swz(j, qf * 4)) = *(const float4*)(zr + qf * 4);
    }
    __syncthreads();
    if (tid < 112) {
        float s = 0.f;
        const float* zr = zb + tid * LDSROW;
#pragma unroll
        for (int d = 0; d < DDIM; d += 4) {
            float4 zv = *(const float4*)(zr + swz(tid, d));
            s += zv.x * zv.x + zv.y * zv.y + zv.z * zv.z + zv.w * zv.w;
        }
        nrm[tid] = s;
    }
    __syncthreads();

    // 3x4 register micro-tile per thread (rows ta*3+r, cols tb*4+c)
    float acc[3][4];
#pragma unroll
    for (int r = 0; r < 3; ++r)
#pragma unroll
        for (int c = 0; c < 4; ++c) acc[r][c] = 0.f;
#pragma unroll
    for (int s = 0; s < 16; ++s) {
        float4 av[3], bv[4];
#pragma unroll
        for (int r = 0; r < 3; ++r) {
            int row = ta * 3 + r;
            av[r] = *(const float4*)(zb + row * LDSROW + swz(row, s * 4));
        }
#pragma unroll
        for (int c = 0; c < 4; ++c) {
            int row = TROWS + tb * 4 + c;
            bv[c] = *(const float4*)(zb + row * LDSROW + swz(row, s * 4));
        }
#pragma unroll
        for (int r = 0; r < 3; ++r)
#pragma unroll
            for (int c = 0; c < 4; ++c) {
                acc[r][c] = fmaf(av[r].x, bv[c].x, acc[r][c]);
                acc[r][c] = fmaf(av[r].y, bv[c].y, acc[r][c]);
                acc[r][c] = fmaf(av[r].z, bv[c].z, acc[r][c]);
                acc[r][c] = fmaf(av[r].w, bv[c].w, acc[r][c]);
            }
    }

    float rs[3][NKER];
#pragma unroll
    for (int r = 0; r < 3; ++r)
#pragma unroll
        for (int k = 0; k < NKER; ++k) rs[r][k] = 0.f;

#pragma unroll
    for (int r = 0; r < 3; ++r) {
        int a = r0 + ta * 3 + r;
        unsigned short h[4][4];   // [c][k], fully unrolled -> registers
#pragma unroll
        for (int c = 0; c < 4; ++c) {
            int b = b0 + tb * 4 + c;
            float d2 = (nrm[ta * 3 + r] + nrm[TROWS + tb * 4 + c]) - 2.f * acc[r][c];
            if (b == a) d2 = 0.f;
            d2 = fmaxf(d2, 0.f);
            float d2e = d2 + 1e-12f;
            float dist = sqrtf(d2e);
#pragma unroll
            for (int k = 0; k < NKER; ++k) {
                float val = ((k & 1) == 0) ? __expf(-d2e * ib2[k]) : __expf(-dist * ib1[k]);
                rs[r][k] += val;
                h[c][k] = f2bf(val);
                if (a < NHALF && b == a + NHALF)          // diagonal partner K(a, a+384)
                    ws[OF_C + k * NHALF + a] = val;
            }
        }
#pragma unroll
        for (int k = 0; k < NKER; ++k) {
            ushort4 us;
            us.x = h[0][k]; us.y = h[1][k]; us.z = h[2][k]; us.w = h[3][k];
            *(ushort4*)(KH + k * K0SZ + a * NTOT + b0 + tb * 4) = us;
        }
    }

#pragma unroll
    for (int off = 8; off > 0; off >>= 1)
#pragma unroll
        for (int r = 0; r < 3; ++r)
#pragma unroll
            for (int k = 0; k < NKER; ++k) rs[r][k] += __shfl_down(rs[r][k], off, 64);
    if (tb == 0) {
#pragma unroll
        for (int k = 0; k < NKER; ++k)
#pragma unroll
            for (int r = 0; r < 3; ++r)
                ws[OF_P + (k * NTILE + bt) * NTOT + r0 + ta * 3 + r] = rs[r][k];
    }
}

// ============ phase 2: split-K gemm (bid<384) or final (k=bid-384) ============
__device__ __forceinline__ void phase2_body(int bid, int tid, float* smem,
                                            const float* __restrict__ bw,
                                            float* __restrict__ ws,
                                            float* __restrict__ out) {
    int wave = tid >> 6, lane = tid & 63;

    if (bid < NB_GEMM) {
        int mb = bid % NMB;
        int t  = bid / NMB;
        int nc = t & 3;
        int t2 = t >> 2;
        int k  = t2 & 3;
        int kh = t2 >> 2;
        int m0 = mb * 64 + wave * 16;
        int n0 = nc * 64;
        int row = lane & 15, quad = lane >> 4;
        const unsigned short* KH  = (const unsigned short*)(ws + OF_KH);
        const unsigned short* STT = (const unsigned short*)(ws + OF_STT);
        const unsigned short* aptr = KH + k * K0SZ + (m0 + row) * NTOT + quad * 8;
        floatx4 acc[4][2];
#pragma unroll
        for (int j = 0; j < 4; ++j)
#pragma unroll
            for (int h = 0; h < 2; ++h) acc[j][h] = (floatx4){0.f, 0.f, 0.f, 0.f};
        int kk0 = kh * (NTOT / 2);
        for (int kk = kk0; kk < kk0 + NTOT / 2; kk += 64) {
            short8 a0 = *(const short8*)(aptr + kk);
            short8 a1 = *(const short8*)(aptr + kk + 32);
#pragma unroll
            for (int j = 0; j < 4; ++j) {
                const unsigned short* bp = STT + (n0 + j * 16 + row) * NTOT + quad * 8 + kk;
                short8 b0 = *(const short8*)(bp);
                short8 b1 = *(const short8*)(bp + 32);
                acc[j][0] = __builtin_amdgcn_mfma_f32_16x16x32_bf16(a0, b0, acc[j][0], 0, 0, 0);
                acc[j][1] = __builtin_amdgcn_mfma_f32_16x16x32_bf16(a1, b1, acc[j][1], 0, 0, 0);
            }
        }
        __syncthreads();
#pragma unroll
        for (int j = 0; j < 4; ++j) {
            const unsigned short* sp = STT + (n0 + j * 16 + row) * NTOT + m0 + quad * 4;
            float p = 0.f;
#pragma unroll
            for (int r = 0; r < 4; ++r) p += (acc[j][0][r] + acc[j][1][r]) * bf2f(sp[r]);
            p += __shfl_down(p, 32, 64);
            p += __shfl_down(p, 16, 64);
            if (lane < 16) smem[wave * 64 + j * 16 + lane] = p;
        }
        __syncthreads();
        if (tid < 64) {
            float s = smem[tid] + smem[64 + tid] + smem[128 + tid] + smem[192 + tid];
            ws[OF_Q0P + (k * NPART + kh * NMB + mb) * PPAD + n0 + tid] = s;
        }
        return;
    }

    int k = bid - NB_GEMM;
    const float* Pk = ws + OF_P + k * (NTILE * NTOT);
    float v[5] = {0.f, 0.f, 0.f, 0.f, 0.f};
    for (int a = tid; a < NTOT; a += 256) {
        float rsx = 0.f, rsy = 0.f;
#pragma unroll
        for (int j = 0; j < 6; ++j)  rsx += Pk[j * NTOT + a];
#pragma unroll
        for (int j = 6; j < 12; ++j) rsy += Pk[j * NTOT + a];
        float rs0 = rsx + rsy;
        float cx = (a < NHALF)  ? ws[OF_C + k * NHALF + a] : 0.f;
        float cy = (a >= NHALF) ? ws[OF_C + k * NHALF + a - NHALF] : 0.f;
        ws[OF_ROWM + k * NTOT + a] = rs0 - cx;
        ws[OF_COLM + k * NTOT + a] = rs0 - cy;
        v[0] += rs0;
        if (a < NHALF) { v[1] += cx; v[2] += rsx; v[4] += rsy; }
        else           { v[3] += rsy; }
    }
#pragma unroll
    for (int off = 32; off > 0; off >>= 1)
#pragma unroll
        for (int j = 0; j < 5; ++j) v[j] += __shfl_down(v[j], off, 64);
    __syncthreads();
    if (lane == 0)
#pragma unroll
        for (int j = 0; j < 5; ++j) smem[wave * 8 + j] = v[j];
    __syncthreads();
    if (tid == 0) {
        float tot0 = smem[0] + smem[8] + smem[16] + smem[24];
        float csum = smem[1] + smem[9] + smem[17] + smem[25];
        float sxx  = smem[2] + smem[10] + smem[18] + smem[26];
        float syy  = smem[3] + smem[11] + smem[19] + smem[27];
        float sxy  = smem[4] + smem[12] + smem[20] + smem[28];
        float b = bw[k];
        float dist0 = sqrtf(1e-12f);
        float dk = ((k & 1) == 0) ? expf(-(dist0 * dist0) / (b * b)) : expf(-dist0 / b);
        ws[OF_SCAL + k * 4 + 0] = tot0 - csum;
        ws[OF_SCAL + k * 4 + 1] = dk;
        double U = ((double)sxx - 384.0 * (double)dk) * (1.0 / 147072.0)
                 + ((double)syy - 384.0 * (double)dk) * (1.0 / 147072.0)
                 - 2.0 * ((double)sxy - (double)csum) * (1.0 / 147456.0);
        out[k * 201] = (float)U;
    }
}

// ============ phase 3: per-perm gathered sums, dual-k per block ============
// 400 blocks: p = bid%200, handles k = bid/200 and k+2 (shares perm/STT loads).
__device__ __forceinline__ void phase3_body(int bid, int tid, float* smem,
                                            const int* __restrict__ perms,
                                            const float* __restrict__ ws,
                                            float* __restrict__ out) {
    if (bid >= 2 * NPER) return;
    int wave = tid >> 6, lane = tid & 63;
    int p  = bid % NPER;
    int kb = bid / NPER;          // 0 or 1
    int k0 = kb, k1 = kb + 2;
    const unsigned short* STT = (const unsigned short*)(ws + OF_STT);
    const unsigned short* KH  = (const unsigned short*)(ws + OF_KH);
    float v0[4] = {0.f, 0.f, 0.f, 0.f};   // rs, cs, pair, qc for k0
    float v1[4] = {0.f, 0.f, 0.f, 0.f};   // same for k1
    for (int i = tid; i < NHALF; i += 256) {
        int a  = perms[p * NTOT + i];
        int bY = perms[p * NTOT + NHALF + i];
        float ss = bf2f(STT[p * NTOT + i]) * bf2f(STT[p * NTOT + NHALF + i]);
        bool diag = (a < NHALF) && (bY == a + NHALF);
        v0[0] += ws[OF_ROWM + k0 * NTOT + a];
        v0[1] += ws[OF_COLM + k0 * NTOT + a];
        float kv0 = bf2f(KH[k0 * K0SZ + a * NTOT + bY]);
        v0[2] += diag ? 0.f : kv0;
        v0[3] += ws[OF_C + k0 * NHALF + i] * ss;
        v1[0] += ws[OF_ROWM + k1 * NTOT + a];
        v1[1] += ws[OF_COLM + k1 * NTOT + a];
        float kv1 = bf2f(KH[k1 * K0SZ + a * NTOT + bY]);
        v1[2] += diag ? 0.f : kv1;
        v1[3] += ws[OF_C + k1 * NHALF + i] * ss;
    }
#pragma unroll
    for (int off = 32; off > 0; off >>= 1)
#pragma unroll
        for (int j = 0; j < 4; ++j) {
            v0[j] += __shfl_down(v0[j], off, 64);
            v1[j] += __shfl_down(v1[j], off, 64);
        }
    if (lane == 0)
#pragma unroll
        for (int j = 0; j < 4; ++j) {
            smem[wave * 8 + j]     = v0[j];
            smem[wave * 8 + 4 + j] = v1[j];
        }
    // lane-parallel Q0P partial sums (24 partials each), wave 0 lanes 0..23
    float q0 = 0.f, q1 = 0.f;
    if (tid < NPART) {
        q0 = ws[OF_Q0P + (k0 * NPART + tid) * PPAD + p];
        q1 = ws[OF_Q0P + (k1 * NPART + tid) * PPAD + p];
    }
#pragma unroll
    for (int off = 16; off > 0; off >>= 1) {
        q0 += __shfl_down(q0, off, 32);
        q1 += __shfl_down(q1, off, 32);
    }
    __syncthreads();
    if (tid == 0) {
#pragma unroll
        for (int kk = 0; kk < 2; ++kk) {
            int k = (kk == 0) ? k0 : k1;
            int o = (kk == 0) ? 0 : 4;
            float qsumf = (kk == 0) ? q0 : q1;
            double rs   = (double)(smem[o + 0] + smem[o + 8] + smem[o + 16] + smem[o + 24]);
            double cs   = (double)(smem[o + 1] + smem[o + 9] + smem[o + 17] + smem[o + 25]);
            double pair = (double)(smem[o + 2] + smem[o + 10] + smem[o + 18] + smem[o + 26]);
            double qc   = (double)(smem[o + 3] + smem[o + 11] + smem[o + 19] + smem[o + 27]);
            double total_mod = (double)ws[OF_SCAL + k * 4 + 0];
            double dk        = (double)ws[OF_SCAL + k * 4 + 1];
            double q = (double)qsumf - qc;
            double sXX = q - 384.0 * dk;
            double sYY = total_mod - rs - cs + q - 384.0 * dk;
            double sXY = rs - q - pair;
            out[k * 201 + 1 + p] =
                (float)(sXX * (1.0 / 147072.0) + sYY * (1.0 / 147072.0) - 2.0 * sXY * (1.0 / 147456.0));
        }
    }
}

// ============ fused cooperative kernel: 3 launches -> 1 launch + 2 grid syncs ============
// 400 blocks x 256 thr; co-residency needs 2 blocks/CU: LDS 35KB -> 4/CU,
// launch_bounds(256,2) caps VGPR at 256 -> >=2/CU. Checked host-side before coop launch.
__global__ __launch_bounds__(256, 2) void k_fused(const float* __restrict__ X,
                                                  const float* __restrict__ Y,
                                                  const float* __restrict__ bw,
                                                  const int* __restrict__ perms,
                                                  float* __restrict__ ws,
                                                  float* __restrict__ out) {
    __shared__ float smem[128 * LDSROW + 128];   // 35 KB; phases 2/3 reuse the prefix
    cg::grid_group grid = cg::this_grid();
    int bid = blockIdx.x, tid = threadIdx.x;

    phase1_body(bid, tid, smem, X, Y, bw, perms, ws);
    __threadfence();   // device-scope: make KH/STT/P/C visible across XCD L2s
    grid.sync();

    if (bid < NB_GEMM + NKER) phase2_body(bid, tid, smem, bw, ws, out);
    __threadfence();
    grid.sync();

    phase3_body(bid, tid, smem, perms, ws, out);
}

// ============ fallback standalone kernels (same bodies, 3 launches) ============
__global__ __launch_bounds__(256) void k_s1(const float* __restrict__ X,
                                            const float* __restrict__ Y,
                                            const float* __restrict__ bw,
                                            const int* __restrict__ perms,
                                            float* __restrict__ ws) {
    __shared__ float smem[128 * LDSROW + 128];
    phase1_body(blockIdx.x, threadIdx.x, smem, X, Y, bw, perms, ws);
}

__global__ __launch_bounds__(256) void k_s2(const float* __restrict__ bw,
                                            float* __restrict__ ws, float* __restrict__ out) {
    __shared__ float smem[256];
    phase2_body(blockIdx.x, threadIdx.x, smem, bw, ws, out);
}

__global__ __launch_bounds__(256) void k_s3(const int* __restrict__ perms,
                                            const float* __restrict__ ws,
                                            float* __restrict__ out) {
    __shared__ float smem[64];
    phase3_body(blockIdx.x, threadIdx.x, smem, perms, ws, out);
}

extern "C" void kernel_launch(void* const* d_in, const int* in_sizes, int n_in,
                              void* d_out, int out_size, void* d_ws, size_t ws_size,
                              hipStream_t stream) {
    const float* X     = (const float*)d_in[0];
    const float* Y     = (const float*)d_in[1];
    const float* bw    = (const float*)d_in[2];
    const int*   perms = (const int*)d_in[3];
    float* ws  = (float*)d_ws;
    float* out = (float*)d_out;

    // Decide coop viability once (pure occupancy query: capture-safe, no stream ops).
    static int coop_ok = -1;
    if (coop_ok < 0) {
        int nb = 0;
        hipError_t e = hipOccupancyMaxActiveBlocksPerMultiprocessor(&nb, k_fused, 256, 0);
        coop_ok = (e == hipSuccess && nb >= 2) ? 1 : 0;   // 2 blocks/CU x 256 CU = 512 >= 400
    }
    if (coop_ok == 1) {
        void* args[6] = {(void*)&X, (void*)&Y, (void*)&bw, (void*)&perms, (void*)&ws, (void*)&out};
        if (hipLaunchCooperativeKernel(k_fused, dim3(NBLK_FUSED), dim3(256), args, 0u, stream)
            == hipSuccess)
            return;
        coop_ok = 0;   // fall through to 3-launch path permanently
    }
    k_s1<<<NHB + NPER, 256, 0, stream>>>(X, Y, bw, perms, ws);
    k_s2<<<NB_GEMM + NKER, 256, 0, stream>>>(bw, ws, out);
    k_s3<<<2 * NPER, 256, 0, stream>>>(perms, ws, out);
}

// Round 5
// 93.138 us; speedup vs baseline: 1.1235x; 1.0035x over previous
//
#include <hip/hip_runtime.h>
#include <hip/hip_cooperative_groups.h>

namespace cg = cooperative_groups;

#define NTOT 768
#define NHALF 384
#define DDIM 64
#define NPER 200
#define PPAD 256
#define NKER 4
#define NMB 12       // m-blocks of 64 rows (gemm)
#define NKH 2        // split-K halves (gemm)
#define NB_GEMM 384  // 12 mb * 4 nc * 4 k * 2 kh
#define NPART (NMB * NKH)
#define NTILE 12     // 768/64 b-tiles (K-build cols)
#define NRT 16       // 768/48 row-tiles (K-build rows)
#define NHB (NRT * NTILE)   // 192 heavy blocks <= 256 CUs -> <=1 heavy/CU
#define TROWS 48
#define LDSROW 68    // float stride per staged row: 16B-aligned
#define NBLK_FUSED 400  // max(phase1 392, phase2 388, phase3 400); <=512 co-resident @2/CU

typedef __attribute__((ext_vector_type(8))) short short8;    // 8 bf16 (4 VGPR)
typedef __attribute__((ext_vector_type(4))) float floatx4;   // MFMA acc

constexpr int K0SZ  = NTOT * NTOT;
constexpr int OF_KH = 0;                                  // bf16 K [4][768][768] (ushort)
constexpr int KH_FLOATS = NKER * K0SZ / 2;
constexpr int OF_P   = OF_KH + KH_FLOATS;                 // fp32 row-sum partials [4][12][768]
constexpr int OF_C   = OF_P + NKER * NTILE * NTOT;        // fp32 packed [384][4k]
constexpr int OF_ROWM = OF_C + NKER * NHALF;              // fp32 packed [768][4k]
constexpr int OF_COLM = OF_ROWM + NKER * NTOT;            // fp32 packed [768][4k]
constexpr int OF_SCAL = OF_COLM + NKER * NTOT;
constexpr int OF_STT  = OF_SCAL + 16;                     // bf16 S^T [PPAD][NTOT]
constexpr int STT_FLOATS = PPAD * NTOT / 2;
constexpr int OF_Q0P  = OF_STT + STT_FLOATS;              // fp32 [4][NPART][PPAD]

__device__ __forceinline__ unsigned short f2bf(float f) {  // RTN
    unsigned int u = __float_as_uint(f);
    return (unsigned short)((u + 0x7FFFu + ((u >> 16) & 1u)) >> 16);
}
__device__ __forceinline__ float bf2f(unsigned short h) {
    return __uint_as_float(((unsigned int)h) << 16);
}
// XOR bank swizzle: spreads stride-4-row column reads across 8 bank groups.
// posf is the float offset within a row (multiple of 4 -> 16B alignment kept).
__device__ __forceinline__ int swz(int row, int posf) {
    return posf ^ (((row >> 2) & 7) << 2);
}

// ============ phase 1: 48x64 K tile build (bid<192) or scatter STT (bid-192) ============
// Heavy tiles FIRST in the grid so the breadth-first dispatcher lands <=1 heavy/CU.
// Per-row summation tree identical to previous versions -> bit-identical outputs.
__device__ __forceinline__ void phase1_body(int bid, int tid, float* smem,
                                            const float* __restrict__ X,
                                            const float* __restrict__ Y,
                                            const float* __restrict__ bw,
                                            const int* __restrict__ perms,
                                            float* __restrict__ ws) {
    float* zb  = smem;
    float* nrm = smem + 112 * LDSROW;
    unsigned short* STT = (unsigned short*)(ws + OF_STT);
    unsigned short* KH  = (unsigned short*)(ws + OF_KH);

    if (bid >= NHB) {
        int sb = bid - NHB;
        if (sb >= NPER) return;
        if (tid < 192) {
            ((uint2*)(STT + sb * NTOT))[tid] = make_uint2(0u, 0u);
            if (sb < PPAD - NPER)
                ((uint2*)(STT + (NPER + sb) * NTOT))[tid] = make_uint2(0u, 0u);
        }
        __syncthreads();
        int v = perms[sb * NTOT + tid];
        STT[sb * NTOT + v] = 0x3F80;  // bf16 1.0
        if (tid < NHALF - 256) {
            int v2 = perms[sb * NTOT + 256 + tid];
            STT[sb * NTOT + v2] = 0x3F80;
        }
        return;  // fused caller: safe, no further block-level sync inside this body
    }

    int rt = bid / NTILE, bt = bid % NTILE;
    int r0 = rt * TROWS, b0 = bt * 64;
    int ta = tid >> 4, tb = tid & 15;

    float ib2[NKER], ib1[NKER];
#pragma unroll
    for (int k = 0; k < NKER; ++k) { float b = bw[k]; ib2[k] = 1.f / (b * b); ib1[k] = 1.f / b; }

    // stage 48 a-rows + 64 b-rows of Z (112 rows x 64 f32), bank-swizzled
#pragma unroll
    for (int it = 0; it < 7; ++it) {
        int idx = it * 256 + tid;       // 0..1791 = 112 rows x 16 float4
        int j = idx >> 4, qf = idx & 15;
        int g = (j < TROWS) ? r0 + j : b0 + (j - TROWS);
        const float* zr = (g < NHALF) ? X + g * DDIM : Y + (g - NHALF) * DDIM;
        *(float4*)(zb + j * LDSROW + swz(j, qf * 4)) = *(const float4*)(zr + qf * 4);
    }
    __syncthreads();
    if (tid < 112) {
        float s = 0.f;
        const float* zr = zb + tid * LDSROW;
#pragma unroll
        for (int d = 0; d < DDIM; d += 4) {
            float4 zv = *(const float4*)(zr + swz(tid, d));
            s += zv.x * zv.x + zv.y * zv.y + zv.z * zv.z + zv.w * zv.w;
        }
        nrm[tid] = s;
    }
    __syncthreads();

    // 3x4 register micro-tile per thread (rows ta*3+r, cols tb*4+c)
    float acc[3][4];
#pragma unroll
    for (int r = 0; r < 3; ++r)
#pragma unroll
        for (int c = 0; c < 4; ++c) acc[r][c] = 0.f;
#pragma unroll
    for (int s = 0; s < 16; ++s) {
        float4 av[3], bv[4];
#pragma unroll
        for (int r = 0; r < 3; ++r) {
            int row = ta * 3 + r;
            av[r] = *(const float4*)(zb + row * LDSROW + swz(row, s * 4));
        }
#pragma unroll
        for (int c = 0; c < 4; ++c) {
            int row = TROWS + tb * 4 + c;
            bv[c] = *(const float4*)(zb + row * LDSROW + swz(row, s * 4));
        }
#pragma unroll
        for (int r = 0; r < 3; ++r)
#pragma unroll
            for (int c = 0; c < 4; ++c) {
                acc[r][c] = fmaf(av[r].x, bv[c].x, acc[r][c]);
                acc[r][c] = fmaf(av[r].y, bv[c].y, acc[r][c]);
                acc[r][c] = fmaf(av[r].z, bv[c].z, acc[r][c]);
                acc[r][c] = fmaf(av[r].w, bv[c].w, acc[r][c]);
            }
    }

    float rs[3][NKER];
#pragma unroll
    for (int r = 0; r < 3; ++r)
#pragma unroll
        for (int k = 0; k < NKER; ++k) rs[r][k] = 0.f;

#pragma unroll
    for (int r = 0; r < 3; ++r) {
        int a = r0 + ta * 3 + r;
        unsigned short h[4][4];   // [c][k], fully unrolled -> registers
#pragma unroll
        for (int c = 0; c < 4; ++c) {
            int b = b0 + tb * 4 + c;
            float d2 = (nrm[ta * 3 + r] + nrm[TROWS + tb * 4 + c]) - 2.f * acc[r][c];
            if (b == a) d2 = 0.f;
            d2 = fmaxf(d2, 0.f);
            float d2e = d2 + 1e-12f;
            float dist = sqrtf(d2e);
#pragma unroll
            for (int k = 0; k < NKER; ++k) {
                float val = ((k & 1) == 0) ? __expf(-d2e * ib2[k]) : __expf(-dist * ib1[k]);
                rs[r][k] += val;
                h[c][k] = f2bf(val);
                if (a < NHALF && b == a + NHALF)          // diagonal partner K(a, a+384)
                    ws[OF_C + a * 4 + k] = val;           // packed [a][4k]
            }
        }
#pragma unroll
        for (int k = 0; k < NKER; ++k) {
            ushort4 us;
            us.x = h[0][k]; us.y = h[1][k]; us.z = h[2][k]; us.w = h[3][k];
            *(ushort4*)(KH + k * K0SZ + a * NTOT + b0 + tb * 4) = us;
        }
    }

#pragma unroll
    for (int off = 8; off > 0; off >>= 1)
#pragma unroll
        for (int r = 0; r < 3; ++r)
#pragma unroll
            for (int k = 0; k < NKER; ++k) rs[r][k] += __shfl_down(rs[r][k], off, 64);
    if (tb == 0) {
#pragma unroll
        for (int k = 0; k < NKER; ++k)
#pragma unroll
            for (int r = 0; r < 3; ++r)
                ws[OF_P + (k * NTILE + bt) * NTOT + r0 + ta * 3 + r] = rs[r][k];
    }
}

// ============ phase 2: split-K gemm (bid<384) or final (k=bid-384) ============
__device__ __forceinline__ void phase2_body(int bid, int tid, float* smem,
                                            const float* __restrict__ bw,
                                            float* __restrict__ ws,
                                            float* __restrict__ out) {
    int wave = tid >> 6, lane = tid & 63;

    if (bid < NB_GEMM) {
        int mb = bid % NMB;
        int t  = bid / NMB;
        int nc = t & 3;
        int t2 = t >> 2;
        int k  = t2 & 3;
        int kh = t2 >> 2;
        int m0 = mb * 64 + wave * 16;
        int n0 = nc * 64;
        int row = lane & 15, quad = lane >> 4;
        const unsigned short* KH  = (const unsigned short*)(ws + OF_KH);
        const unsigned short* STT = (const unsigned short*)(ws + OF_STT);
        const unsigned short* aptr = KH + k * K0SZ + (m0 + row) * NTOT + quad * 8;
        floatx4 acc[4][2];
#pragma unroll
        for (int j = 0; j < 4; ++j)
#pragma unroll
            for (int h = 0; h < 2; ++h) acc[j][h] = (floatx4){0.f, 0.f, 0.f, 0.f};
        int kk0 = kh * (NTOT / 2);
        for (int kk = kk0; kk < kk0 + NTOT / 2; kk += 64) {
            short8 a0 = *(const short8*)(aptr + kk);
            short8 a1 = *(const short8*)(aptr + kk + 32);
#pragma unroll
            for (int j = 0; j < 4; ++j) {
                const unsigned short* bp = STT + (n0 + j * 16 + row) * NTOT + quad * 8 + kk;
                short8 b0 = *(const short8*)(bp);
                short8 b1 = *(const short8*)(bp + 32);
                acc[j][0] = __builtin_amdgcn_mfma_f32_16x16x32_bf16(a0, b0, acc[j][0], 0, 0, 0);
                acc[j][1] = __builtin_amdgcn_mfma_f32_16x16x32_bf16(a1, b1, acc[j][1], 0, 0, 0);
            }
        }
        __syncthreads();
#pragma unroll
        for (int j = 0; j < 4; ++j) {
            const unsigned short* sp = STT + (n0 + j * 16 + row) * NTOT + m0 + quad * 4;
            float p = 0.f;
#pragma unroll
            for (int r = 0; r < 4; ++r) p += (acc[j][0][r] + acc[j][1][r]) * bf2f(sp[r]);
            p += __shfl_down(p, 32, 64);
            p += __shfl_down(p, 16, 64);
            if (lane < 16) smem[wave * 64 + j * 16 + lane] = p;
        }
        __syncthreads();
        if (tid < 64) {
            float s = smem[tid] + smem[64 + tid] + smem[128 + tid] + smem[192 + tid];
            ws[OF_Q0P + (k * NPART + kh * NMB + mb) * PPAD + n0 + tid] = s;
        }
        return;
    }

    int k = bid - NB_GEMM;
    const float* Pk = ws + OF_P + k * (NTILE * NTOT);
    float v[5] = {0.f, 0.f, 0.f, 0.f, 0.f};
    for (int a = tid; a < NTOT; a += 256) {
        float rsx = 0.f, rsy = 0.f;
#pragma unroll
        for (int j = 0; j < 6; ++j)  rsx += Pk[j * NTOT + a];
#pragma unroll
        for (int j = 6; j < 12; ++j) rsy += Pk[j * NTOT + a];
        float rs0 = rsx + rsy;
        float cx = (a < NHALF)  ? ws[OF_C + a * 4 + k] : 0.f;
        float cy = (a >= NHALF) ? ws[OF_C + (a - NHALF) * 4 + k] : 0.f;
        ws[OF_ROWM + a * 4 + k] = rs0 - cx;   // packed [a][4k]
        ws[OF_COLM + a * 4 + k] = rs0 - cy;   // packed [a][4k]
        v[0] += rs0;
        if (a < NHALF) { v[1] += cx; v[2] += rsx; v[4] += rsy; }
        else           { v[3] += rsy; }
    }
#pragma unroll
    for (int off = 32; off > 0; off >>= 1)
#pragma unroll
        for (int j = 0; j < 5; ++j) v[j] += __shfl_down(v[j], off, 64);
    __syncthreads();
    if (lane == 0)
#pragma unroll
        for (int j = 0; j < 5; ++j) smem[wave * 8 + j] = v[j];
    __syncthreads();
    if (tid == 0) {
        float tot0 = smem[0] + smem[8] + smem[16] + smem[24];
        float csum = smem[1] + smem[9] + smem[17] + smem[25];
        float sxx  = smem[2] + smem[10] + smem[18] + smem[26];
        float syy  = smem[3] + smem[11] + smem[19] + smem[27];
        float sxy  = smem[4] + smem[12] + smem[20] + smem[28];
        float b = bw[k];
        float dist0 = sqrtf(1e-12f);
        float dk = ((k & 1) == 0) ? expf(-(dist0 * dist0) / (b * b)) : expf(-dist0 / b);
        ws[OF_SCAL + k * 4 + 0] = tot0 - csum;
        ws[OF_SCAL + k * 4 + 1] = dk;
        double U = ((double)sxx - 384.0 * (double)dk) * (1.0 / 147072.0)
                 + ((double)syy - 384.0 * (double)dk) * (1.0 / 147072.0)
                 - 2.0 * ((double)sxy - (double)csum) * (1.0 / 147456.0);
        out[k * 201] = (float)U;
    }
}

// ============ phase 3: per-perm gathered sums, dual-k per block ============
// 400 blocks: p = bid%200, handles k = bid/200 and k+2. Packed [a][4k] planes:
// one float4 line serves BOTH k-values -> 5 scattered loads per index (was 8).
__device__ __forceinline__ void phase3_body(int bid, int tid, float* smem,
                                            const int* __restrict__ perms,
                                            const float* __restrict__ ws,
                                            float* __restrict__ out) {
    if (bid >= 2 * NPER) return;
    int wave = tid >> 6, lane = tid & 63;
    int p  = bid % NPER;
    int kb = bid / NPER;          // 0 or 1
    int k0 = kb, k1 = kb + 2;
    const unsigned short* STT = (const unsigned short*)(ws + OF_STT);
    const unsigned short* KH  = (const unsigned short*)(ws + OF_KH);
    float v0[4] = {0.f, 0.f, 0.f, 0.f};   // rs, cs, pair, qc for k0
    float v1[4] = {0.f, 0.f, 0.f, 0.f};   // same for k1
    for (int i = tid; i < NHALF; i += 256) {
        int a  = perms[p * NTOT + i];
        int bY = perms[p * NTOT + NHALF + i];
        float ss = bf2f(STT[p * NTOT + i]) * bf2f(STT[p * NTOT + NHALF + i]);
        bool diag = (a < NHALF) && (bY == a + NHALF);
        float4 rw = *(const float4*)(ws + OF_ROWM + a * 4);
        float4 cl = *(const float4*)(ws + OF_COLM + a * 4);
        float4 cc = *(const float4*)(ws + OF_C + i * 4);
        // component select by kb (0 -> {x,z}, 1 -> {y,w}); branchless cndmask
        float rw0 = kb ? rw.y : rw.x, rw1 = kb ? rw.w : rw.z;
        float cl0 = kb ? cl.y : cl.x, cl1 = kb ? cl.w : cl.z;
        float cc0 = kb ? cc.y : cc.x, cc1 = kb ? cc.w : cc.z;
        float kv0 = bf2f(KH[k0 * K0SZ + a * NTOT + bY]);
        float kv1 = bf2f(KH[k1 * K0SZ + a * NTOT + bY]);
        v0[0] += rw0;
        v0[1] += cl0;
        v0[2] += diag ? 0.f : kv0;
        v0[3] += cc0 * ss;
        v1[0] += rw1;
        v1[1] += cl1;
        v1[2] += diag ? 0.f : kv1;
        v1[3] += cc1 * ss;
    }
#pragma unroll
    for (int off = 32; off > 0; off >>= 1)
#pragma unroll
        for (int j = 0; j < 4; ++j) {
            v0[j] += __shfl_down(v0[j], off, 64);
            v1[j] += __shfl_down(v1[j], off, 64);
        }
    if (lane == 0)
#pragma unroll
        for (int j = 0; j < 4; ++j) {
            smem[wave * 8 + j]     = v0[j];
            smem[wave * 8 + 4 + j] = v1[j];
        }
    // lane-parallel Q0P partial sums (24 partials each), wave 0 lanes 0..23
    float q0 = 0.f, q1 = 0.f;
    if (tid < NPART) {
        q0 = ws[OF_Q0P + (k0 * NPART + tid) * PPAD + p];
        q1 = ws[OF_Q0P + (k1 * NPART + tid) * PPAD + p];
    }
#pragma unroll
    for (int off = 16; off > 0; off >>= 1) {
        q0 += __shfl_down(q0, off, 32);
        q1 += __shfl_down(q1, off, 32);
    }
    __syncthreads();
    if (tid == 0) {
#pragma unroll
        for (int kk = 0; kk < 2; ++kk) {
            int k = (kk == 0) ? k0 : k1;
            int o = (kk == 0) ? 0 : 4;
            float qsumf = (kk == 0) ? q0 : q1;
            double rs   = (double)(smem[o + 0] + smem[o + 8] + smem[o + 16] + smem[o + 24]);
            double cs   = (double)(smem[o + 1] + smem[o + 9] + smem[o + 17] + smem[o + 25]);
            double pair = (double)(smem[o + 2] + smem[o + 10] + smem[o + 18] + smem[o + 26]);
            double qc   = (double)(smem[o + 3] + smem[o + 11] + smem[o + 19] + smem[o + 27]);
            double total_mod = (double)ws[OF_SCAL + k * 4 + 0];
            double dk        = (double)ws[OF_SCAL + k * 4 + 1];
            double q = (double)qsumf - qc;
            double sXX = q - 384.0 * dk;
            double sYY = total_mod - rs - cs + q - 384.0 * dk;
            double sXY = rs - q - pair;
            out[k * 201 + 1 + p] =
                (float)(sXX * (1.0 / 147072.0) + sYY * (1.0 / 147072.0) - 2.0 * sXY * (1.0 / 147456.0));
        }
    }
}

// ============ fused cooperative kernel: 3 launches -> 1 launch + 2 grid syncs ============
// 400 blocks x 256 thr; co-residency needs 2 blocks/CU: LDS 35KB -> 4/CU,
// launch_bounds(256,2) caps VGPR at 256 -> >=2/CU. Checked host-side before coop launch.
__global__ __launch_bounds__(256, 2) void k_fused(const float* __restrict__ X,
                                                  const float* __restrict__ Y,
                                                  const float* __restrict__ bw,
                                                  const int* __restrict__ perms,
                                                  float* __restrict__ ws,
                                                  float* __restrict__ out) {
    __shared__ float smem[128 * LDSROW + 128];   // 35 KB; phases 2/3 reuse the prefix
    cg::grid_group grid = cg::this_grid();
    int bid = blockIdx.x, tid = threadIdx.x;

    phase1_body(bid, tid, smem, X, Y, bw, perms, ws);
    __threadfence();   // device-scope: make KH/STT/P/C visible across XCD L2s
    grid.sync();

    if (bid < NB_GEMM + NKER) phase2_body(bid, tid, smem, bw, ws, out);
    __threadfence();
    grid.sync();

    phase3_body(bid, tid, smem, perms, ws, out);
}

// ============ fallback standalone kernels (same bodies, 3 launches) ============
__global__ __launch_bounds__(256) void k_s1(const float* __restrict__ X,
                                            const float* __restrict__ Y,
                                            const float* __restrict__ bw,
                                            const int* __restrict__ perms,
                                            float* __restrict__ ws) {
    __shared__ float smem[128 * LDSROW + 128];
    phase1_body(blockIdx.x, threadIdx.x, smem, X, Y, bw, perms, ws);
}

__global__ __launch_bounds__(256) void k_s2(const float* __restrict__ bw,
                                            float* __restrict__ ws, float* __restrict__ out) {
    __shared__ float smem[256];
    phase2_body(blockIdx.x, threadIdx.x, smem, bw, ws, out);
}

__global__ __launch_bounds__(256) void k_s3(const int* __restrict__ perms,
                                            const float* __restrict__ ws,
                                            float* __restrict__ out) {
    __shared__ float smem[64];
    phase3_body(blockIdx.x, threadIdx.x, smem, perms, ws, out);
}

extern "C" void kernel_launch(void* const* d_in, const int* in_sizes, int n_in,
                              void* d_out, int out_size, void* d_ws, size_t ws_size,
                              hipStream_t stream) {
    const float* X     = (const float*)d_in[0];
    const float* Y     = (const float*)d_in[1];
    const float* bw    = (const float*)d_in[2];
    const int*   perms = (const int*)d_in[3];
    float* ws  = (float*)d_ws;
    float* out = (float*)d_out;

    // Decide coop viability once (pure occupancy query: capture-safe, no stream ops).
    static int coop_ok = -1;
    if (coop_ok < 0) {
        int nb = 0;
        hipError_t e = hipOccupancyMaxActiveBlocksPerMultiprocessor(&nb, k_fused, 256, 0);
        coop_ok = (e == hipSuccess && nb >= 2) ? 1 : 0;   // 2 blocks/CU x 256 CU = 512 >= 400
    }
    if (coop_ok == 1) {
        void* args[6] = {(void*)&X, (void*)&Y, (void*)&bw, (void*)&perms, (void*)&ws, (void*)&out};
        if (hipLaunchCooperativeKernel(k_fused, dim3(NBLK_FUSED), dim3(256), args, 0u, stream)
            == hipSuccess)
            return;
        coop_ok = 0;   // fall through to 3-launch path permanently
    }
    k_s1<<<NHB + NPER, 256, 0, stream>>>(X, Y, bw, perms, ws);
    k_s2<<<NB_GEMM + NKER, 256, 0, stream>>>(bw, ws, out);
    k_s3<<<2 * NPER, 256, 0, stream>>>(perms, ws, out);
}